// Round 13
// baseline (206.056 us; speedup 1.0000x reference)
//
#include <hip/hip_runtime.h>

// Attention, non-standard masking (masked scores -> 0.0 before softmax).
// B=16, S=2048, D=256, fp32 in/out. No-max streaming softmax (scores ~N(0,1)).
// exp2-based: Q pre-scaled by log2e/16.
//
// v12 = v7's PROVEN attn (95us: counted-vmcnt quad-buffer pipeline, packed
// mask from L2) + BALLOT-FREE coalesced mask-pack prepass (v7's 150us prepass
// was latency-bound on a ballot dependency chain; the fix is each lane packs
// one 32-col word from 8 int4 loads -- wave reads 8KB contiguous, writes
// 256B contiguous, pure BW ~45us, fused with the K/V conversions).
// Evidence (r7-r12): mask from L2 -> attn 95us; mask from HBM any way ->
// 155-190us. Latency class of the mask is the only variable that matters.

#define B_  16
#define S_  2048
#define D_  256
#define NT_ 64            // 32-kv tiles per batch
#define TILE_BYTES 16384

typedef short bf16x8 __attribute__((ext_vector_type(8)));
typedef float f32x4  __attribute__((ext_vector_type(4)));

__device__ __forceinline__ unsigned short f2bf(float x) {
    union { float f; unsigned u; } c; c.f = x;
    unsigned u = c.u;
    u += 0x7FFFu + ((u >> 16) & 1u);   // round-to-nearest-even
    return (unsigned short)(u >> 16);
}

#define GLDS(g, l) __builtin_amdgcn_global_load_lds( \
    (const __attribute__((address_space(1))) void*)(g), \
    (__attribute__((address_space(3))) void*)(l), 16, 0, 0)

#define WAITVM(N) asm volatile("s_waitcnt vmcnt(" #N ")" ::: "memory")

// ---------------- fused prepass ---------------------------------------------
// bid [0,4096):     K -> [32kv][512B] img, byte(kv,d)=kv*512 + (d*2 ^ ((kv&7)<<4))
// bid [4096,8192):  V -> [256d][64B] img, byte(d,kv)=d*64 + (kv*2 ^ (((d>>1)&3)<<4))
// bid [8192,16384): mask -> pm[row*64 + w]; bit j of word w = mask[row][w*32+j]
//                   (ballot-free: lane w packs 8 int4; wave = 1 row)
__global__ __launch_bounds__(256)
void prep_all(const float* __restrict__ k, const float* __restrict__ v,
              const int* __restrict__ mask,
              char* __restrict__ kbf, char* __restrict__ vtbf,
              unsigned* __restrict__ pm)
{
    const int bid = blockIdx.x;
    if (bid < 4096) {
        const int gid = bid * 256 + threadIdx.x;          // 2^20 threads
        const int d8  = gid & 31;
        const int kv  = (gid >> 5) & 2047;
        const int b   = gid >> 16;
        const float* src = k + (((size_t)(b * S_ + kv)) << 8) + d8 * 8;
        const float4 f0 = *(const float4*)src;
        const float4 f1 = *(const float4*)(src + 4);
        bf16x8 h;
        h[0] = (short)f2bf(f0.x); h[1] = (short)f2bf(f0.y);
        h[2] = (short)f2bf(f0.z); h[3] = (short)f2bf(f0.w);
        h[4] = (short)f2bf(f1.x); h[5] = (short)f2bf(f1.y);
        h[6] = (short)f2bf(f1.z); h[7] = (short)f2bf(f1.w);
        const int tile = kv >> 5, kvl = kv & 31;
        char* dst = kbf + (((size_t)(b * NT_ + tile)) << 14)
                        + (kvl << 9) + ((d8 * 16) ^ ((kvl & 7) << 4));
        *(bf16x8*)dst = h;
    } else if (bid < 8192) {
        const int gid  = (bid - 4096) * 256 + threadIdx.x;
        const int d    = gid & 255;
        const int g    = (gid >> 8) & 3;                  // kv group of 8
        const int tile = (gid >> 10) & 63;
        const int b    = gid >> 16;
        const int kv0  = tile * 32 + g * 8;
        const float* src = v + (((size_t)(b * S_ + kv0)) << 8) + d;
        bf16x8 h;
        #pragma unroll
        for (int j = 0; j < 8; ++j) h[j] = (short)f2bf(src[(size_t)j << 8]);
        char* dst = vtbf + (((size_t)(b * NT_ + tile)) << 14)
                         + (d << 6) + ((g * 16) ^ (((d >> 1) & 3) << 4));
        *(bf16x8*)dst = h;
    } else {
        // mask pack: 4 rows per block (1 row per wave); lane l packs word l.
        const int wv   = threadIdx.x >> 6;
        const int lane = threadIdx.x & 63;
        const int row  = (bid - 8192) * 4 + wv;           // 0..32767
        const char* src = (const char*)mask + (size_t)row * 8192 + lane * 128;
        unsigned wbits = 0;
        #pragma unroll
        for (int j = 0; j < 8; ++j) {
            const int4 m = *(const int4*)(src + j * 16);
            wbits |= (unsigned)(m.x != 0) << (4 * j);
            wbits |= (unsigned)(m.y != 0) << (4 * j + 1);
            wbits |= (unsigned)(m.z != 0) << (4 * j + 2);
            wbits |= (unsigned)(m.w != 0) << (4 * j + 3);
        }
        pm[(size_t)row * 64 + lane] = wbits;
    }
}

// --------------------------------- main (v7 verbatim) ------------------------
// 256 thr / 4 waves; wave wid owns q-rows qt*128 + wid*32 .. +32; all 64 tiles.
__global__ __launch_bounds__(256, 1)
void attn_main(const float* __restrict__ q, const unsigned* __restrict__ pm,
               const char* __restrict__ kbf, const char* __restrict__ vtbf,
               float* __restrict__ out)
{
    // [0,65536) K quad-buf; [65536,131072) Vt quad-buf; [131072,139264) P
    __shared__ alignas(128) char lds[139264];

    const int tid  = threadIdx.x;
    const int wid  = tid >> 6;
    const int lane = tid & 63;
    const int ln15 = lane & 15;
    const int quad = lane >> 4;
    const int swzK = (ln15 & 7) << 4;          // K row XOR key (bits 4-6)
    const int swzA = ((ln15 >> 1) & 3) << 4;   // Vt/P row XOR key (bits 4-5)

    const int bid = blockIdx.x;
    const int bx  = (bid & 7) * 32 + (bid >> 3);   // XCD-chunked swizzle
    const int b   = bx >> 4;
    const int qt  = bx & 15;
    const int qw  = qt * 128 + wid * 32;           // wave owns 32 q-rows

    // Q A-fragments (2 sets of 16 rows), pre-scaled by log2(e)/sqrt(256)
    const float QS = 0.09016844f;
    bf16x8 aq[2][8];
    #pragma unroll
    for (int s = 0; s < 2; ++s) {
        const float* qrow = q + ((size_t)(b * S_ + qw + s * 16 + ln15)) * D_;
        #pragma unroll
        for (int ks = 0; ks < 8; ++ks) {
            const float4 f0 = *(const float4*)(qrow + ks * 32 + quad * 8);
            const float4 f1 = *(const float4*)(qrow + ks * 32 + quad * 8 + 4);
            bf16x8 a;
            a[0] = (short)f2bf(f0.x * QS); a[1] = (short)f2bf(f0.y * QS);
            a[2] = (short)f2bf(f0.z * QS); a[3] = (short)f2bf(f0.w * QS);
            a[4] = (short)f2bf(f1.x * QS); a[5] = (short)f2bf(f1.y * QS);
            a[6] = (short)f2bf(f1.z * QS); a[7] = (short)f2bf(f1.w * QS);
            aq[s][ks] = a;
        }
    }

    bf16x8 ones;
    #pragma unroll
    for (int e = 0; e < 8; ++e) ones[e] = (short)0x3F80;

    f32x4 oacc[2][16];
    #pragma unroll
    for (int s = 0; s < 2; ++s)
        #pragma unroll
        for (int i = 0; i < 16; ++i) oacc[s][i] = (f32x4){0.f, 0.f, 0.f, 0.f};
    f32x4 lacc[2];
    lacc[0] = (f32x4){0.f, 0.f, 0.f, 0.f};
    lacc[1] = (f32x4){0.f, 0.f, 0.f, 0.f};

    const char* ktile = kbf  + (((size_t)b * NT_) << 14);
    const char* vtile = vtbf + (((size_t)b * NT_) << 14);
    char* pw = lds + 131072 + wid * 2048;
    const int cc = wid * 4;   // this wave's 4 staging chunks (of 16) per tile

    const unsigned* pmrow = pm + ((size_t)(b * S_ + qw + 4 * quad)) * 64;
    unsigned mreg[4][8];

    // ---- prologue: issue groups 0,1,2 (16 VMEM ops each, in order) ----
    #pragma unroll
    for (int t = 0; t < 3; ++t) {
        #pragma unroll
        for (int c = 0; c < 4; ++c) {
            GLDS(ktile + t * 16384 + (cc + c) * 1024 + lane * 16,
                 lds +         t * 16384 + (cc + c) * 1024);
            GLDS(vtile + t * 16384 + (cc + c) * 1024 + lane * 16,
                 lds + 65536 + t * 16384 + (cc + c) * 1024);
        }
        #pragma unroll
        for (int s = 0; s < 2; ++s)
            #pragma unroll
            for (int r = 0; r < 4; ++r)
                mreg[t][s * 4 + r] = pmrow[(size_t)(s * 16 + r) * 64 + t];
    }

#define PHASE(T, CUR, CNT, ISSUE)                                               \
    {                                                                           \
        WAITVM(CNT);                                                            \
        __builtin_amdgcn_sched_barrier(0);                                      \
        __builtin_amdgcn_s_barrier();                                           \
        __builtin_amdgcn_sched_barrier(0);                                      \
        if (ISSUE) {                                                            \
            const int tn  = (T) + 3;                                            \
            const int bn  = ((CUR) + 3) & 3;                                    \
            const char* kg_ = ktile + ((size_t)tn << 14);                       \
            const char* vg_ = vtile + ((size_t)tn << 14);                       \
            _Pragma("unroll")                                                   \
            for (int c = 0; c < 4; ++c) {                                       \
                GLDS(kg_ + (cc + c) * 1024 + lane * 16,                         \
                     lds + bn * 16384 +         (cc + c) * 1024);               \
                GLDS(vg_ + (cc + c) * 1024 + lane * 16,                         \
                     lds + 65536 + bn * 16384 + (cc + c) * 1024);               \
            }                                                                   \
            _Pragma("unroll")                                                   \
            for (int s = 0; s < 2; ++s)                                         \
                _Pragma("unroll")                                               \
                for (int r = 0; r < 4; ++r)                                     \
                    mreg[bn][s * 4 + r] = pmrow[(size_t)(s * 16 + r) * 64 + tn]; \
            __builtin_amdgcn_sched_barrier(0);                                  \
        }                                                                       \
        const char* kl = lds + (CUR) * 16384;                                   \
        f32x4 sacc[2][2];                                                       \
        sacc[0][0] = (f32x4){0.f, 0.f, 0.f, 0.f};                               \
        sacc[0][1] = (f32x4){0.f, 0.f, 0.f, 0.f};                               \
        sacc[1][0] = (f32x4){0.f, 0.f, 0.f, 0.f};                               \
        sacc[1][1] = (f32x4){0.f, 0.f, 0.f, 0.f};                               \
        _Pragma("unroll")                                                       \
        for (int ks = 0; ks < 8; ++ks) {                                        \
            _Pragma("unroll")                                                   \
            for (int nt = 0; nt < 2; ++nt) {                                    \
                const int off = ((nt * 16 + ln15) << 9)                         \
                              + (((ks << 6) + (quad << 4)) ^ swzK);             \
                const bf16x8 bk = *(const bf16x8*)(kl + off);                   \
                sacc[0][nt] = __builtin_amdgcn_mfma_f32_16x16x32_bf16(aq[0][ks], bk, sacc[0][nt], 0, 0, 0); \
                sacc[1][nt] = __builtin_amdgcn_mfma_f32_16x16x32_bf16(aq[1][ks], bk, sacc[1][nt], 0, 0, 0); \
            }                                                                   \
        }                                                                       \
        _Pragma("unroll")                                                       \
        for (int s = 0; s < 2; ++s) {                                           \
            _Pragma("unroll")                                                   \
            for (int nt = 0; nt < 2; ++nt) {                                    \
                _Pragma("unroll")                                               \
                for (int r = 0; r < 4; ++r) {                                   \
                    const float p = ((mreg[CUR][s * 4 + r] >> (nt * 16 + ln15)) & 1u) \
                                  ? exp2f(sacc[s][nt][r]) : 1.0f;               \
                    const int row  = s * 16 + 4 * quad + r;                     \
                    const int boff = (row << 6)                                 \
                                   + ((nt * 32 + ln15 * 2) ^ (((row >> 1) & 3) << 4)); \
                    *(unsigned short*)(pw + boff) = f2bf(p);                    \
                }                                                               \
            }                                                                   \
        }                                                                       \
        const bf16x8 ap0 = *(const bf16x8*)(pw + (ln15 << 6)        + ((quad << 4) ^ swzA)); \
        const bf16x8 ap1 = *(const bf16x8*)(pw + ((16 + ln15) << 6) + ((quad << 4) ^ swzA)); \
        const char* vl = lds + 65536 + (CUR) * 16384;                           \
        lacc[0] = __builtin_amdgcn_mfma_f32_16x16x32_bf16(ap0, ones, lacc[0], 0, 0, 0); \
        lacc[1] = __builtin_amdgcn_mfma_f32_16x16x32_bf16(ap1, ones, lacc[1], 0, 0, 0); \
        _Pragma("unroll")                                                       \
        for (int nt2 = 0; nt2 < 16; ++nt2) {                                    \
            const int voff = ((nt2 * 16 + ln15) << 6) + ((quad << 4) ^ swzA);   \
            const bf16x8 bv = *(const bf16x8*)(vl + voff);                      \
            oacc[0][nt2] = __builtin_amdgcn_mfma_f32_16x16x32_bf16(ap0, bv, oacc[0][nt2], 0, 0, 0); \
            oacc[1][nt2] = __builtin_amdgcn_mfma_f32_16x16x32_bf16(ap1, bv, oacc[1][nt2], 0, 0, 0); \
        }                                                                       \
    }

    // main loop: phases 0..59 (full pattern), then peeled tail 60..63
    for (int t4 = 0; t4 < 15; ++t4) {
        const int t = t4 * 4;
        PHASE(t + 0, 0, 32, 1);
        PHASE(t + 1, 1, 32, 1);
        PHASE(t + 2, 2, 32, 1);
        PHASE(t + 3, 3, 32, 1);
    }
    PHASE(60, 0, 32, 1);   // issues group 63
    PHASE(61, 1, 32, 0);
    PHASE(62, 2, 16, 0);
    PHASE(63, 3,  0, 0);
#undef PHASE

    // ---- epilogue: normalize and store ----
    #pragma unroll
    for (int s = 0; s < 2; ++s) {
        #pragma unroll
        for (int r = 0; r < 4; ++r) {
            const float inv = 1.0f / lacc[s][r];
            float* orow = out + ((size_t)(b * S_ + qw + s * 16 + 4 * quad + r)) * D_ + ln15;
            #pragma unroll
            for (int nt2 = 0; nt2 < 16; ++nt2)
                orow[nt2 * 16] = oacc[s][nt2][r] * inv;
        }
    }
}

// ---------------- fallback (round-1 kernel, used if ws too small) -----------
#define QT 128
#define KTF 64
#define NW 8
#define KSTR 264
#define VSTR 72
#define PSTR 72

__global__ __launch_bounds__(512, 2)
void attn_fused_v1(const float* __restrict__ q, const float* __restrict__ k,
                   const float* __restrict__ v, const int* __restrict__ mask,
                   float* __restrict__ out)
{
    __shared__ unsigned short Kl[KTF * KSTR];
    __shared__ unsigned short Vt[D_ * VSTR];
    __shared__ unsigned short Pl[NW][16 * PSTR];

    const int tid  = threadIdx.x;
    const int wid  = tid >> 6;
    const int lane = tid & 63;
    const int ln15 = lane & 15;
    const int quad = lane >> 4;
    const int bid = blockIdx.x;
    const int bx  = (bid & 7) * 32 + (bid >> 3);
    const int b  = bx >> 4;
    const int qt = bx & 15;
    const int qw = qt * QT + wid * 16;

    const float* qb = q + ((size_t)b * S_ + qw) * D_;
    const float* kb = k + (size_t)b * S_ * D_;
    const float* vb = v + (size_t)b * S_ * D_;
    const int*   mb = mask + ((size_t)b * S_ + qw) * (size_t)S_;

    bf16x8 aq[8];
    {
        const float* qrow = qb + (size_t)ln15 * D_;
        #pragma unroll
        for (int ks = 0; ks < 8; ++ks) {
            const float4 f0 = *(const float4*)(qrow + ks * 32 + quad * 8);
            const float4 f1 = *(const float4*)(qrow + ks * 32 + quad * 8 + 4);
            bf16x8 a;
            a[0] = (short)f2bf(f0.x * 0.0625f); a[1] = (short)f2bf(f0.y * 0.0625f);
            a[2] = (short)f2bf(f0.z * 0.0625f); a[3] = (short)f2bf(f0.w * 0.0625f);
            a[4] = (short)f2bf(f1.x * 0.0625f); a[5] = (short)f2bf(f1.y * 0.0625f);
            a[6] = (short)f2bf(f1.z * 0.0625f); a[7] = (short)f2bf(f1.w * 0.0625f);
            aq[ks] = a;
        }
    }
    bf16x8 ones;
    #pragma unroll
    for (int e = 0; e < 8; ++e) ones[e] = (short)0x3F80;
    f32x4 oacc[16];
    #pragma unroll
    for (int i = 0; i < 16; ++i) oacc[i] = (f32x4){0.f, 0.f, 0.f, 0.f};
    f32x4 lacc = (f32x4){0.f, 0.f, 0.f, 0.f};
    const int kst_c0 = (tid & 63) * 4;

    for (int kt2 = 0; kt2 < S_ / KTF; ++kt2) {
        const int kvbase = kt2 * KTF;
        int mval[4][4];
        #pragma unroll
        for (int nt = 0; nt < 4; ++nt)
            #pragma unroll
            for (int r = 0; r < 4; ++r)
                mval[nt][r] = mb[(size_t)(4 * quad + r) * S_ + kvbase + nt * 16 + ln15];
        __syncthreads();
        {
            const float* ks_ = kb + (size_t)kvbase * D_;
            #pragma unroll
            for (int pass = 0; pass < 8; ++pass) {
                const int r = pass * 8 + wid;
                const float4 f = *(const float4*)(ks_ + (size_t)r * D_ + kst_c0);
                ushort4 hh;
                hh.x = f2bf(f.x); hh.y = f2bf(f.y); hh.z = f2bf(f.z); hh.w = f2bf(f.w);
                *(ushort4*)&Kl[r * KSTR + kst_c0] = hh;
            }
        }
        {
            const float* vs_ = vb + (size_t)kvbase * D_;
            #pragma unroll
            for (int pass = 0; pass < 8; ++pass) {
                const int idx = pass * 8 + wid;
                const int kv  = (idx & 3) * 16 + ln15;
                const int d0  = (idx >> 2) * 16 + 4 * quad;
                const float4 f = *(const float4*)(vs_ + (size_t)kv * D_ + d0);
                Vt[(d0 + 0) * VSTR + kv] = f2bf(f.x);
                Vt[(d0 + 1) * VSTR + kv] = f2bf(f.y);
                Vt[(d0 + 2) * VSTR + kv] = f2bf(f.z);
                Vt[(d0 + 3) * VSTR + kv] = f2bf(f.w);
            }
        }
        __syncthreads();
        f32x4 sacc[4];
        #pragma unroll
        for (int nt = 0; nt < 4; ++nt) sacc[nt] = (f32x4){0.f, 0.f, 0.f, 0.f};
        #pragma unroll
        for (int ks = 0; ks < 8; ++ks) {
            #pragma unroll
            for (int nt = 0; nt < 4; ++nt) {
                const bf16x8 bk =
                    *(const bf16x8*)&Kl[(nt * 16 + ln15) * KSTR + ks * 32 + quad * 8];
                sacc[nt] = __builtin_amdgcn_mfma_f32_16x16x32_bf16(aq[ks], bk, sacc[nt], 0, 0, 0);
            }
        }
        unsigned short* pwv = Pl[wid];
        #pragma unroll
        for (int nt = 0; nt < 4; ++nt) {
            #pragma unroll
            for (int r = 0; r < 4; ++r) {
                const float s = sacc[nt][r];
                const float p = (mval[nt][r] != 0) ? __expf(s) : 1.0f;
                pwv[(4 * quad + r) * PSTR + nt * 16 + ln15] = f2bf(p);
            }
        }
        #pragma unroll
        for (int ks2 = 0; ks2 < 2; ++ks2) {
            const bf16x8 ap = *(const bf16x8*)&pwv[ln15 * PSTR + ks2 * 32 + quad * 8];
            lacc = __builtin_amdgcn_mfma_f32_16x16x32_bf16(ap, ones, lacc, 0, 0, 0);
            #pragma unroll
            for (int nt2 = 0; nt2 < 16; ++nt2) {
                const bf16x8 bv =
                    *(const bf16x8*)&Vt[(nt2 * 16 + ln15) * VSTR + ks2 * 32 + quad * 8];
                oacc[nt2] = __builtin_amdgcn_mfma_f32_16x16x32_bf16(ap, bv, oacc[nt2], 0, 0, 0);
            }
        }
    }
    #pragma unroll
    for (int r = 0; r < 4; ++r) {
        const float inv = 1.0f / lacc[r];
        float* orow = out + ((size_t)b * S_ + qw + 4 * quad + r) * D_ + ln15;
        #pragma unroll
        for (int nt2 = 0; nt2 < 16; ++nt2)
            orow[nt2 * 16] = oacc[nt2][r] * inv;
    }
}

extern "C" void kernel_launch(void* const* d_in, const int* in_sizes, int n_in,
                              void* d_out, int out_size, void* d_ws, size_t ws_size,
                              hipStream_t stream) {
    const float* q    = (const float*)d_in[0];
    const float* k    = (const float*)d_in[1];
    const float* v    = (const float*)d_in[2];
    const int*   mask = (const int*)d_in[3];
    float*       out  = (float*)d_out;

    const size_t one  = (size_t)B_ * NT_ * TILE_BYTES;            // 16.78 MB
    const size_t pmsz = (size_t)B_ * S_ * 64 * 4;                 //  8.39 MB
    if (ws_size >= 2 * one + pmsz) {
        char*     kbf  = (char*)d_ws;
        char*     vtbf = kbf + one;
        unsigned* pmp  = (unsigned*)(vtbf + one);
        prep_all<<<16384, 256, 0, stream>>>(k, v, mask, kbf, vtbf, pmp);
        attn_main<<<256, 256, 0, stream>>>(q, pmp, kbf, vtbf, out);
    } else {
        attn_fused_v1<<<256, 512, 0, stream>>>(q, k, v, mask, out);
    }
}

// Round 14
// 204.685 us; speedup vs baseline: 1.0067x; 1.0067x over previous
//
#include <hip/hip_runtime.h>

// Attention, non-standard masking (masked scores -> 0.0 before softmax).
// B=16, S=2048, D=256, fp32 in/out. No-max streaming softmax (scores ~N(0,1)).
// exp2-based: Q pre-scaled by log2e/16.
//
// v14: mask pack FUSED into attn kernel, per block, into LDS.
//  Each block consumes exactly its own 128 q-rows' mask = 1 MB contiguous.
//  Pack phase (start of kernel): unit-stride int4 wave loads (1KB/instr),
//  nibble pack, per-wave 512B LDS transpose -> pm[128][64] u32 in LDS (32KB).
//  Pipeline: v7's counted-vmcnt schedule, K/V TRIPLE-buffered (96KB), groups
//  of 8 GLDS, distance 2, s_waitcnt vmcnt(8) steady (0 only at final phase).
//  Mask consumption = ds_read_b32 broadcast (lgkm, not vmcnt) -> in-loop VMEM
//  is pure global_load_lds (the v7 95us property, now with zero pm traffic).
//  prep_all = proven K/V bf16 pre-swizzled tile image conversion only (~7us).

#define B_  16
#define S_  2048
#define D_  256
#define NT_ 64            // 32-kv tiles per batch
#define TILE_BYTES 16384

typedef short bf16x8 __attribute__((ext_vector_type(8)));
typedef float f32x4  __attribute__((ext_vector_type(4)));

__device__ __forceinline__ unsigned short f2bf(float x) {
    union { float f; unsigned u; } c; c.f = x;
    unsigned u = c.u;
    u += 0x7FFFu + ((u >> 16) & 1u);   // round-to-nearest-even
    return (unsigned short)(u >> 16);
}

#define GLDS(g, l) __builtin_amdgcn_global_load_lds( \
    (const __attribute__((address_space(1))) void*)(g), \
    (__attribute__((address_space(3))) void*)(l), 16, 0, 0)

#define WAITVM(N) asm volatile("s_waitcnt vmcnt(" #N ")" ::: "memory")
#define SCHEDB()  __builtin_amdgcn_sched_barrier(0)

// ---------------- prepass: K/V -> bf16 pre-swizzled tile images -------------
// bid [0,4096):    K -> [32kv][512B] img, byte(kv,d)=kv*512 + (d*2 ^ ((kv&7)<<4))
// bid [4096,8192): V -> [256d][64B] img, byte(d,kv)=d*64 + (kv*2 ^ (((d>>1)&3)<<4))
__global__ __launch_bounds__(256)
void prep_all(const float* __restrict__ k, const float* __restrict__ v,
              char* __restrict__ kbf, char* __restrict__ vtbf)
{
    const int bid = blockIdx.x;
    if (bid < 4096) {
        const int gid = bid * 256 + threadIdx.x;          // 2^20 threads
        const int d8  = gid & 31;
        const int kv  = (gid >> 5) & 2047;
        const int b   = gid >> 16;
        const float* src = k + (((size_t)(b * S_ + kv)) << 8) + d8 * 8;
        const float4 f0 = *(const float4*)src;
        const float4 f1 = *(const float4*)(src + 4);
        bf16x8 h;
        h[0] = (short)f2bf(f0.x); h[1] = (short)f2bf(f0.y);
        h[2] = (short)f2bf(f0.z); h[3] = (short)f2bf(f0.w);
        h[4] = (short)f2bf(f1.x); h[5] = (short)f2bf(f1.y);
        h[6] = (short)f2bf(f1.z); h[7] = (short)f2bf(f1.w);
        const int tile = kv >> 5, kvl = kv & 31;
        char* dst = kbf + (((size_t)(b * NT_ + tile)) << 14)
                        + (kvl << 9) + ((d8 * 16) ^ ((kvl & 7) << 4));
        *(bf16x8*)dst = h;
    } else {
        const int gid  = (bid - 4096) * 256 + threadIdx.x;
        const int d    = gid & 255;
        const int g    = (gid >> 8) & 3;                  // kv group of 8
        const int tile = (gid >> 10) & 63;
        const int b    = gid >> 16;
        const int kv0  = tile * 32 + g * 8;
        const float* src = v + (((size_t)(b * S_ + kv0)) << 8) + d;
        bf16x8 h;
        #pragma unroll
        for (int j = 0; j < 8; ++j) h[j] = (short)f2bf(src[(size_t)j << 8]);
        char* dst = vtbf + (((size_t)(b * NT_ + tile)) << 14)
                         + (d << 6) + ((g * 16) ^ (((d >> 1) & 3) << 4));
        *(bf16x8*)dst = h;
    }
}

// --------------------------------- main -------------------------------------
// 256 thr / 4 waves; wave wid owns q-rows qt*128 + wid*32 .. +32; all 64 tiles.
__global__ __launch_bounds__(256, 1)
void attn_main(const float* __restrict__ q, const int* __restrict__ mask,
               const char* __restrict__ kbf, const char* __restrict__ vtbf,
               float* __restrict__ out)
{
    // K 3x16KB [0,49152); Vt 3x16KB [49152,98304); P [98304,106496);
    // pm [106496,139264): [128 rows][64 words] u32
    __shared__ alignas(128) char lds[139264];

    const int tid  = threadIdx.x;
    const int wid  = tid >> 6;
    const int lane = tid & 63;
    const int ln15 = lane & 15;
    const int quad = lane >> 4;
    const int swzK = (ln15 & 7) << 4;          // K row XOR key (bits 4-6)
    const int swzA = ((ln15 >> 1) & 3) << 4;   // Vt/P row XOR key (bits 4-5)

    const int bid = blockIdx.x;
    const int bx  = (bid & 7) * 32 + (bid >> 3);   // XCD-chunked swizzle
    const int b   = bx >> 4;
    const int qt  = bx & 15;
    const int qw  = qt * 128 + wid * 32;           // wave owns 32 q-rows

    // Q A-fragments (2 sets of 16 rows), pre-scaled by log2(e)/sqrt(256)
    const float QS = 0.09016844f;
    bf16x8 aq[2][8];
    #pragma unroll
    for (int s = 0; s < 2; ++s) {
        const float* qrow = q + ((size_t)(b * S_ + qw + s * 16 + ln15)) * D_;
        #pragma unroll
        for (int ks = 0; ks < 8; ++ks) {
            const float4 f0 = *(const float4*)(qrow + ks * 32 + quad * 8);
            const float4 f1 = *(const float4*)(qrow + ks * 32 + quad * 8 + 4);
            bf16x8 a;
            a[0] = (short)f2bf(f0.x * QS); a[1] = (short)f2bf(f0.y * QS);
            a[2] = (short)f2bf(f0.z * QS); a[3] = (short)f2bf(f0.w * QS);
            a[4] = (short)f2bf(f1.x * QS); a[5] = (short)f2bf(f1.y * QS);
            a[6] = (short)f2bf(f1.z * QS); a[7] = (short)f2bf(f1.w * QS);
            aq[s][ks] = a;
        }
    }
    SCHEDB();

    const char* ktile = kbf  + (((size_t)b * NT_) << 14);
    const char* vtile = vtbf + (((size_t)b * NT_) << 14);
    char* pw = lds + 98304 + wid * 2048;
    unsigned* pmL = (unsigned*)(lds + 106496);
    const int cc = wid * 4;   // this wave's 4 staging chunks (of 16) per tile

    // ---- prologue FIRST: issue GLDS groups for tiles 0,1 (16 ops) ----
    // (they land under the ~45us pack phase below)
    #pragma unroll
    for (int t = 0; t < 2; ++t)
        #pragma unroll
        for (int c = 0; c < 4; ++c) {
            GLDS(ktile + t * 16384 + (cc + c) * 1024 + lane * 16,
                 lds +         t * 16384 + (cc + c) * 1024);
            GLDS(vtile + t * 16384 + (cc + c) * 1024 + lane * 16,
                 lds + 49152 + t * 16384 + (cc + c) * 1024);
        }
    SCHEDB();

    // ---- pack phase: this wave's 32 mask rows -> pm LDS (coalesced) ----
    {
        char* scratch = lds + 98304 + wid * 512;   // overlays P (unused yet)
        const char* mrow = (const char*)mask + ((size_t)(b * S_) + qw) * 8192;
        for (int r = 0; r < 32; ++r) {
            const char* src = mrow + (size_t)r * 8192 + lane * 16;
            int4 m[8];
            #pragma unroll
            for (int j = 0; j < 8; ++j)
                m[j] = *(const int4*)(src + j * 1024);   // 1KB/instr, unit-stride
            #pragma unroll
            for (int j = 0; j < 8; ++j) {
                const unsigned nib = (unsigned)(m[j].x != 0)
                                   | ((unsigned)(m[j].y != 0) << 1)
                                   | ((unsigned)(m[j].z != 0) << 2)
                                   | ((unsigned)(m[j].w != 0) << 3);
                scratch[j * 64 + lane] = (char)nib;
            }
            const unsigned long long u =
                *(const unsigned long long*)(scratch + lane * 8);
            unsigned w = 0;
            #pragma unroll
            for (int i = 0; i < 8; ++i)
                w |= ((unsigned)(u >> (8 * i)) & 0xFu) << (4 * i);
            pmL[(wid * 32 + r) * 64 + lane] = w;   // word `lane` of this row
        }
    }
    SCHEDB();

    bf16x8 ones;
    #pragma unroll
    for (int e = 0; e < 8; ++e) ones[e] = (short)0x3F80;

    f32x4 oacc[2][16];
    #pragma unroll
    for (int s = 0; s < 2; ++s)
        #pragma unroll
        for (int i = 0; i < 16; ++i) oacc[s][i] = (f32x4){0.f, 0.f, 0.f, 0.f};
    f32x4 lacc[2];
    lacc[0] = (f32x4){0.f, 0.f, 0.f, 0.f};
    lacc[1] = (f32x4){0.f, 0.f, 0.f, 0.f};

#define PHASE(T, CUR, BN, CNT)                                                  \
    {                                                                           \
        WAITVM(CNT);                                                            \
        SCHEDB();                                                               \
        __builtin_amdgcn_s_barrier();                                           \
        SCHEDB();                                                               \
        if ((T) + 2 < NT_) {                                                    \
            const int tn = (T) + 2;                                             \
            const char* kg_ = ktile + ((size_t)tn << 14);                       \
            const char* vg_ = vtile + ((size_t)tn << 14);                       \
            _Pragma("unroll")                                                   \
            for (int c = 0; c < 4; ++c) {                                       \
                GLDS(kg_ + (cc + c) * 1024 + lane * 16,                         \
                     lds + (BN) * 16384 +         (cc + c) * 1024);             \
                GLDS(vg_ + (cc + c) * 1024 + lane * 16,                         \
                     lds + 49152 + (BN) * 16384 + (cc + c) * 1024);             \
            }                                                                   \
            SCHEDB();                                                           \
        }                                                                       \
        const char* kl = lds + (CUR) * 16384;                                   \
        f32x4 sacc[2][2];                                                       \
        sacc[0][0] = (f32x4){0.f, 0.f, 0.f, 0.f};                               \
        sacc[0][1] = (f32x4){0.f, 0.f, 0.f, 0.f};                               \
        sacc[1][0] = (f32x4){0.f, 0.f, 0.f, 0.f};                               \
        sacc[1][1] = (f32x4){0.f, 0.f, 0.f, 0.f};                               \
        _Pragma("unroll")                                                       \
        for (int ks = 0; ks < 8; ++ks) {                                        \
            _Pragma("unroll")                                                   \
            for (int nt = 0; nt < 2; ++nt) {                                    \
                const int off = ((nt * 16 + ln15) << 9)                         \
                              + (((ks << 6) + (quad << 4)) ^ swzK);             \
                const bf16x8 bk = *(const bf16x8*)(kl + off);                   \
                sacc[0][nt] = __builtin_amdgcn_mfma_f32_16x16x32_bf16(aq[0][ks], bk, sacc[0][nt], 0, 0, 0); \
                sacc[1][nt] = __builtin_amdgcn_mfma_f32_16x16x32_bf16(aq[1][ks], bk, sacc[1][nt], 0, 0, 0); \
            }                                                                   \
        }                                                                       \
        _Pragma("unroll")                                                       \
        for (int s = 0; s < 2; ++s) {                                           \
            _Pragma("unroll")                                                   \
            for (int r = 0; r < 4; ++r) {                                       \
                const int row = s * 16 + 4 * quad + r;                          \
                const unsigned w = pmL[(wid * 32 + row) * 64 + (T)];            \
                _Pragma("unroll")                                               \
                for (int nt = 0; nt < 2; ++nt) {                                \
                    const float p = ((w >> (nt * 16 + ln15)) & 1u)              \
                                  ? exp2f(sacc[s][nt][r]) : 1.0f;               \
                    const int boff = (row << 6)                                 \
                                   + ((nt * 32 + ln15 * 2) ^ (((row >> 1) & 3) << 4)); \
                    *(unsigned short*)(pw + boff) = f2bf(p);                    \
                }                                                               \
            }                                                                   \
        }                                                                       \
        const bf16x8 ap0 = *(const bf16x8*)(pw + (ln15 << 6)        + ((quad << 4) ^ swzA)); \
        const bf16x8 ap1 = *(const bf16x8*)(pw + ((16 + ln15) << 6) + ((quad << 4) ^ swzA)); \
        const char* vl = lds + 49152 + (CUR) * 16384;                           \
        lacc[0] = __builtin_amdgcn_mfma_f32_16x16x32_bf16(ap0, ones, lacc[0], 0, 0, 0); \
        lacc[1] = __builtin_amdgcn_mfma_f32_16x16x32_bf16(ap1, ones, lacc[1], 0, 0, 0); \
        _Pragma("unroll")                                                       \
        for (int nt2 = 0; nt2 < 16; ++nt2) {                                    \
            const int voff = ((nt2 * 16 + ln15) << 6) + ((quad << 4) ^ swzA);   \
            const bf16x8 bv = *(const bf16x8*)(vl + voff);                      \
            oacc[0][nt2] = __builtin_amdgcn_mfma_f32_16x16x32_bf16(ap0, bv, oacc[0][nt2], 0, 0, 0); \
            oacc[1][nt2] = __builtin_amdgcn_mfma_f32_16x16x32_bf16(ap1, bv, oacc[1][nt2], 0, 0, 0); \
        }                                                                       \
    }

    // phases 0..62 in a x3-unrolled loop (buffer = phase % 3), 63 peeled
    for (int t3 = 0; t3 < 21; ++t3) {
        const int t = t3 * 3;
        PHASE(t + 0, 0, 2, 8);
        PHASE(t + 1, 1, 0, 8);
        PHASE(t + 2, 2, 1, 8);
    }
    PHASE(63, 0, 2, 0);   // 63 % 3 == 0; no issue; full drain
#undef PHASE

    // ---- epilogue: normalize and store ----
    #pragma unroll
    for (int s = 0; s < 2; ++s) {
        #pragma unroll
        for (int r = 0; r < 4; ++r) {
            const float inv = 1.0f / lacc[s][r];
            float* orow = out + ((size_t)(b * S_ + qw + s * 16 + 4 * quad + r)) * D_ + ln15;
            #pragma unroll
            for (int nt2 = 0; nt2 < 16; ++nt2)
                orow[nt2 * 16] = oacc[s][nt2][r] * inv;
        }
    }
}

// ---------------- fallback (round-1 kernel, used if ws too small) -----------
#define QT 128
#define KTF 64
#define NW 8
#define KSTR 264
#define VSTR 72
#define PSTR 72

__global__ __launch_bounds__(512, 2)
void attn_fused_v1(const float* __restrict__ q, const float* __restrict__ k,
                   const float* __restrict__ v, const int* __restrict__ mask,
                   float* __restrict__ out)
{
    __shared__ unsigned short Kl[KTF * KSTR];
    __shared__ unsigned short Vt[D_ * VSTR];
    __shared__ unsigned short Pl[NW][16 * PSTR];

    const int tid  = threadIdx.x;
    const int wid  = tid >> 6;
    const int lane = tid & 63;
    const int ln15 = lane & 15;
    const int quad = lane >> 4;
    const int bid = blockIdx.x;
    const int bx  = (bid & 7) * 32 + (bid >> 3);
    const int b  = bx >> 4;
    const int qt = bx & 15;
    const int qw = qt * QT + wid * 16;

    const float* qb = q + ((size_t)b * S_ + qw) * D_;
    const float* kb = k + (size_t)b * S_ * D_;
    const float* vb = v + (size_t)b * S_ * D_;
    const int*   mb = mask + ((size_t)b * S_ + qw) * (size_t)S_;

    bf16x8 aq[8];
    {
        const float* qrow = qb + (size_t)ln15 * D_;
        #pragma unroll
        for (int ks = 0; ks < 8; ++ks) {
            const float4 f0 = *(const float4*)(qrow + ks * 32 + quad * 8);
            const float4 f1 = *(const float4*)(qrow + ks * 32 + quad * 8 + 4);
            bf16x8 a;
            a[0] = (short)f2bf(f0.x * 0.0625f); a[1] = (short)f2bf(f0.y * 0.0625f);
            a[2] = (short)f2bf(f0.z * 0.0625f); a[3] = (short)f2bf(f0.w * 0.0625f);
            a[4] = (short)f2bf(f1.x * 0.0625f); a[5] = (short)f2bf(f1.y * 0.0625f);
            a[6] = (short)f2bf(f1.z * 0.0625f); a[7] = (short)f2bf(f1.w * 0.0625f);
            aq[ks] = a;
        }
    }
    bf16x8 ones;
    #pragma unroll
    for (int e = 0; e < 8; ++e) ones[e] = (short)0x3F80;
    f32x4 oacc[16];
    #pragma unroll
    for (int i = 0; i < 16; ++i) oacc[i] = (f32x4){0.f, 0.f, 0.f, 0.f};
    f32x4 lacc = (f32x4){0.f, 0.f, 0.f, 0.f};
    const int kst_c0 = (tid & 63) * 4;

    for (int kt2 = 0; kt2 < S_ / KTF; ++kt2) {
        const int kvbase = kt2 * KTF;
        int mval[4][4];
        #pragma unroll
        for (int nt = 0; nt < 4; ++nt)
            #pragma unroll
            for (int r = 0; r < 4; ++r)
                mval[nt][r] = mb[(size_t)(4 * quad + r) * S_ + kvbase + nt * 16 + ln15];
        __syncthreads();
        {
            const float* ks_ = kb + (size_t)kvbase * D_;
            #pragma unroll
            for (int pass = 0; pass < 8; ++pass) {
                const int r = pass * 8 + wid;
                const float4 f = *(const float4*)(ks_ + (size_t)r * D_ + kst_c0);
                ushort4 hh;
                hh.x = f2bf(f.x); hh.y = f2bf(f.y); hh.z = f2bf(f.z); hh.w = f2bf(f.w);
                *(ushort4*)&Kl[r * KSTR + kst_c0] = hh;
            }
        }
        {
            const float* vs_ = vb + (size_t)kvbase * D_;
            #pragma unroll
            for (int pass = 0; pass < 8; ++pass) {
                const int idx = pass * 8 + wid;
                const int kv  = (idx & 3) * 16 + ln15;
                const int d0  = (idx >> 2) * 16 + 4 * quad;
                const float4 f = *(const float4*)(vs_ + (size_t)kv * D_ + d0);
                Vt[(d0 + 0) * VSTR + kv] = f2bf(f.x);
                Vt[(d0 + 1) * VSTR + kv] = f2bf(f.y);
                Vt[(d0 + 2) * VSTR + kv] = f2bf(f.z);
                Vt[(d0 + 3) * VSTR + kv] = f2bf(f.w);
            }
        }
        __syncthreads();
        f32x4 sacc[4];
        #pragma unroll
        for (int nt = 0; nt < 4; ++nt) sacc[nt] = (f32x4){0.f, 0.f, 0.f, 0.f};
        #pragma unroll
        for (int ks = 0; ks < 8; ++ks) {
            #pragma unroll
            for (int nt = 0; nt < 4; ++nt) {
                const bf16x8 bk =
                    *(const bf16x8*)&Kl[(nt * 16 + ln15) * KSTR + ks * 32 + quad * 8];
                sacc[nt] = __builtin_amdgcn_mfma_f32_16x16x32_bf16(aq[ks], bk, sacc[nt], 0, 0, 0);
            }
        }
        unsigned short* pwv = Pl[wid];
        #pragma unroll
        for (int nt = 0; nt < 4; ++nt) {
            #pragma unroll
            for (int r = 0; r < 4; ++r) {
                const float s = sacc[nt][r];
                const float p = (mval[nt][r] != 0) ? __expf(s) : 1.0f;
                pwv[(4 * quad + r) * PSTR + nt * 16 + ln15] = f2bf(p);
            }
        }
        #pragma unroll
        for (int ks2 = 0; ks2 < 2; ++ks2) {
            const bf16x8 ap = *(const bf16x8*)&pwv[ln15 * PSTR + ks2 * 32 + quad * 8];
            lacc = __builtin_amdgcn_mfma_f32_16x16x32_bf16(ap, ones, lacc, 0, 0, 0);
            #pragma unroll
            for (int nt2 = 0; nt2 < 16; ++nt2) {
                const bf16x8 bv =
                    *(const bf16x8*)&Vt[(nt2 * 16 + ln15) * VSTR + ks2 * 32 + quad * 8];
                oacc[nt2] = __builtin_amdgcn_mfma_f32_16x16x32_bf16(ap, bv, oacc[nt2], 0, 0, 0);
            }
        }
    }
    #pragma unroll
    for (int r = 0; r < 4; ++r) {
        const float inv = 1.0f / lacc[r];
        float* orow = out + ((size_t)b * S_ + qw + 4 * quad + r) * D_ + ln15;
        #pragma unroll
        for (int nt2 = 0; nt2 < 16; ++nt2)
            orow[nt2 * 16] = oacc[nt2][r] * inv;
    }
}

extern "C" void kernel_launch(void* const* d_in, const int* in_sizes, int n_in,
                              void* d_out, int out_size, void* d_ws, size_t ws_size,
                              hipStream_t stream) {
    const float* q    = (const float*)d_in[0];
    const float* k    = (const float*)d_in[1];
    const float* v    = (const float*)d_in[2];
    const int*   mask = (const int*)d_in[3];
    float*       out  = (float*)d_out;

    const size_t one = (size_t)B_ * NT_ * TILE_BYTES;   // 16.78 MB
    if (ws_size >= 2 * one) {
        char* kbf  = (char*)d_ws;
        char* vtbf = kbf + one;
        prep_all<<<8192, 256, 0, stream>>>(k, v, kbf, vtbf);
        attn_main<<<256, 256, 0, stream>>>(q, mask, kbf, vtbf, out);
    } else {
        attn_fused_v1<<<256, 512, 0, stream>>>(q, k, v, mask, out);
    }
}

// Round 15
// 204.387 us; speedup vs baseline: 1.0082x; 1.0015x over previous
//
#include <hip/hip_runtime.h>

// Attention, non-standard masking (masked scores -> 0.0 before softmax).
// B=16, S=2048, D=256, fp32 in/out. No-max streaming softmax (scores ~N(0,1)).
// exp2-based: Q pre-scaled by log2e/16.
//
// v15 = v7's PROVEN 95us attn (counted-vmcnt quad-buffer pipeline, packed
// mask from L2) + standalone COALESCED mask-pack:
//   pack segment: 4096 blocks x 8 rows; per row two unit-stride 4KB
//   block-loads (thread t -> int4 @ t*16), nibble -> 512B LDS scratch ->
//   64 threads gather u64 -> pm[row*64+w]. High occupancy (512B LDS) ->
//   TLP hides latency -> BW-bound (~45us), unlike v12's stride-128 pack
//   (110us) and the fused 1-block/CU packs (v11/v14, regressions).

#define B_  16
#define S_  2048
#define D_  256
#define NT_ 64            // 32-kv tiles per batch
#define TILE_BYTES 16384

typedef short bf16x8 __attribute__((ext_vector_type(8)));
typedef float f32x4  __attribute__((ext_vector_type(4)));

__device__ __forceinline__ unsigned short f2bf(float x) {
    union { float f; unsigned u; } c; c.f = x;
    unsigned u = c.u;
    u += 0x7FFFu + ((u >> 16) & 1u);   // round-to-nearest-even
    return (unsigned short)(u >> 16);
}

#define GLDS(g, l) __builtin_amdgcn_global_load_lds( \
    (const __attribute__((address_space(1))) void*)(g), \
    (__attribute__((address_space(3))) void*)(l), 16, 0, 0)

#define WAITVM(N) asm volatile("s_waitcnt vmcnt(" #N ")" ::: "memory")

// ---------------- fused prepass ---------------------------------------------
// bid [0,4096):     K -> [32kv][512B] img, byte(kv,d)=kv*512 + (d*2 ^ ((kv&7)<<4))
// bid [4096,8192):  V -> [256d][64B] img, byte(d,kv)=d*64 + (kv*2 ^ (((d>>1)&3)<<4))
// bid [8192,12288): mask -> pm[row*64 + w]; bit j of word w = mask[row][w*32+j]
__global__ __launch_bounds__(256)
void prep_all(const float* __restrict__ k, const float* __restrict__ v,
              const int* __restrict__ mask,
              char* __restrict__ kbf, char* __restrict__ vtbf,
              unsigned* __restrict__ pm)
{
    const int bid = blockIdx.x;
    if (bid < 4096) {
        const int gid = bid * 256 + threadIdx.x;          // 2^20 threads
        const int d8  = gid & 31;
        const int kv  = (gid >> 5) & 2047;
        const int b   = gid >> 16;
        const float* src = k + (((size_t)(b * S_ + kv)) << 8) + d8 * 8;
        const float4 f0 = *(const float4*)src;
        const float4 f1 = *(const float4*)(src + 4);
        bf16x8 h;
        h[0] = (short)f2bf(f0.x); h[1] = (short)f2bf(f0.y);
        h[2] = (short)f2bf(f0.z); h[3] = (short)f2bf(f0.w);
        h[4] = (short)f2bf(f1.x); h[5] = (short)f2bf(f1.y);
        h[6] = (short)f2bf(f1.z); h[7] = (short)f2bf(f1.w);
        const int tile = kv >> 5, kvl = kv & 31;
        char* dst = kbf + (((size_t)(b * NT_ + tile)) << 14)
                        + (kvl << 9) + ((d8 * 16) ^ ((kvl & 7) << 4));
        *(bf16x8*)dst = h;
    } else if (bid < 8192) {
        const int gid  = (bid - 4096) * 256 + threadIdx.x;
        const int d    = gid & 255;
        const int g    = (gid >> 8) & 3;                  // kv group of 8
        const int tile = (gid >> 10) & 63;
        const int b    = gid >> 16;
        const int kv0  = tile * 32 + g * 8;
        const float* src = v + (((size_t)(b * S_ + kv0)) << 8) + d;
        bf16x8 h;
        #pragma unroll
        for (int j = 0; j < 8; ++j) h[j] = (short)f2bf(src[(size_t)j << 8]);
        char* dst = vtbf + (((size_t)(b * NT_ + tile)) << 14)
                         + (d << 6) + ((g * 16) ^ (((d >> 1) & 3) << 4));
        *(bf16x8*)dst = h;
    } else {
        // mask pack: 8 rows per block, fully coalesced.
        __shared__ unsigned char scr[512];
        const int t    = threadIdx.x;
        const int row0 = (bid - 8192) * 8;
        const char* mb = (const char*)mask + (size_t)row0 * 8192;
        for (int r = 0; r < 8; ++r) {
            const int4 a = *(const int4*)(mb + (size_t)r * 8192 + t * 16);
            const int4 c = *(const int4*)(mb + (size_t)r * 8192 + 4096 + t * 16);
            __syncthreads();   // scr free (prev row's readers done)
            scr[t] = (unsigned char)((unsigned)(a.x != 0)
                   | ((unsigned)(a.y != 0) << 1)
                   | ((unsigned)(a.z != 0) << 2)
                   | ((unsigned)(a.w != 0) << 3));
            scr[256 + t] = (unsigned char)((unsigned)(c.x != 0)
                         | ((unsigned)(c.y != 0) << 1)
                         | ((unsigned)(c.z != 0) << 2)
                         | ((unsigned)(c.w != 0) << 3));
            __syncthreads();
            if (t < 64) {
                const unsigned long long u = *(const unsigned long long*)(scr + 8 * t);
                unsigned w = 0;
                #pragma unroll
                for (int i = 0; i < 8; ++i)
                    w |= ((unsigned)(u >> (8 * i)) & 0xFu) << (4 * i);
                pm[(size_t)(row0 + r) * 64 + t] = w;
            }
        }
    }
}

// --------------------------------- main (v7 verbatim, 95us proven) ----------
// 256 thr / 4 waves; wave wid owns q-rows qt*128 + wid*32 .. +32; all 64 tiles.
__global__ __launch_bounds__(256, 1)
void attn_main(const float* __restrict__ q, const unsigned* __restrict__ pm,
               const char* __restrict__ kbf, const char* __restrict__ vtbf,
               float* __restrict__ out)
{
    // [0,65536) K quad-buf; [65536,131072) Vt quad-buf; [131072,139264) P
    __shared__ alignas(128) char lds[139264];

    const int tid  = threadIdx.x;
    const int wid  = tid >> 6;
    const int lane = tid & 63;
    const int ln15 = lane & 15;
    const int quad = lane >> 4;
    const int swzK = (ln15 & 7) << 4;          // K row XOR key (bits 4-6)
    const int swzA = ((ln15 >> 1) & 3) << 4;   // Vt/P row XOR key (bits 4-5)

    const int bid = blockIdx.x;
    const int bx  = (bid & 7) * 32 + (bid >> 3);   // XCD-chunked swizzle
    const int b   = bx >> 4;
    const int qt  = bx & 15;
    const int qw  = qt * 128 + wid * 32;           // wave owns 32 q-rows

    // Q A-fragments (2 sets of 16 rows), pre-scaled by log2(e)/sqrt(256)
    const float QS = 0.09016844f;
    bf16x8 aq[2][8];
    #pragma unroll
    for (int s = 0; s < 2; ++s) {
        const float* qrow = q + ((size_t)(b * S_ + qw + s * 16 + ln15)) * D_;
        #pragma unroll
        for (int ks = 0; ks < 8; ++ks) {
            const float4 f0 = *(const float4*)(qrow + ks * 32 + quad * 8);
            const float4 f1 = *(const float4*)(qrow + ks * 32 + quad * 8 + 4);
            bf16x8 a;
            a[0] = (short)f2bf(f0.x * QS); a[1] = (short)f2bf(f0.y * QS);
            a[2] = (short)f2bf(f0.z * QS); a[3] = (short)f2bf(f0.w * QS);
            a[4] = (short)f2bf(f1.x * QS); a[5] = (short)f2bf(f1.y * QS);
            a[6] = (short)f2bf(f1.z * QS); a[7] = (short)f2bf(f1.w * QS);
            aq[s][ks] = a;
        }
    }

    bf16x8 ones;
    #pragma unroll
    for (int e = 0; e < 8; ++e) ones[e] = (short)0x3F80;

    f32x4 oacc[2][16];
    #pragma unroll
    for (int s = 0; s < 2; ++s)
        #pragma unroll
        for (int i = 0; i < 16; ++i) oacc[s][i] = (f32x4){0.f, 0.f, 0.f, 0.f};
    f32x4 lacc[2];
    lacc[0] = (f32x4){0.f, 0.f, 0.f, 0.f};
    lacc[1] = (f32x4){0.f, 0.f, 0.f, 0.f};

    const char* ktile = kbf  + (((size_t)b * NT_) << 14);
    const char* vtile = vtbf + (((size_t)b * NT_) << 14);
    char* pw = lds + 131072 + wid * 2048;
    const int cc = wid * 4;   // this wave's 4 staging chunks (of 16) per tile

    const unsigned* pmrow = pm + ((size_t)(b * S_ + qw + 4 * quad)) * 64;
    unsigned mreg[4][8];

    // ---- prologue: issue groups 0,1,2 (16 VMEM ops each, in order) ----
    #pragma unroll
    for (int t = 0; t < 3; ++t) {
        #pragma unroll
        for (int c = 0; c < 4; ++c) {
            GLDS(ktile + t * 16384 + (cc + c) * 1024 + lane * 16,
                 lds +         t * 16384 + (cc + c) * 1024);
            GLDS(vtile + t * 16384 + (cc + c) * 1024 + lane * 16,
                 lds + 65536 + t * 16384 + (cc + c) * 1024);
        }
        #pragma unroll
        for (int s = 0; s < 2; ++s)
            #pragma unroll
            for (int r = 0; r < 4; ++r)
                mreg[t][s * 4 + r] = pmrow[(size_t)(s * 16 + r) * 64 + t];
    }

#define PHASE(T, CUR, CNT, ISSUE)                                               \
    {                                                                           \
        WAITVM(CNT);                                                            \
        __builtin_amdgcn_sched_barrier(0);                                      \
        __builtin_amdgcn_s_barrier();                                           \
        __builtin_amdgcn_sched_barrier(0);                                      \
        if (ISSUE) {                                                            \
            const int tn  = (T) + 3;                                            \
            const int bn  = ((CUR) + 3) & 3;                                    \
            const char* kg_ = ktile + ((size_t)tn << 14);                       \
            const char* vg_ = vtile + ((size_t)tn << 14);                       \
            _Pragma("unroll")                                                   \
            for (int c = 0; c < 4; ++c) {                                       \
                GLDS(kg_ + (cc + c) * 1024 + lane * 16,                         \
                     lds + bn * 16384 +         (cc + c) * 1024);               \
                GLDS(vg_ + (cc + c) * 1024 + lane * 16,                         \
                     lds + 65536 + bn * 16384 + (cc + c) * 1024);               \
            }                                                                   \
            _Pragma("unroll")                                                   \
            for (int s = 0; s < 2; ++s)                                         \
                _Pragma("unroll")                                               \
                for (int r = 0; r < 4; ++r)                                     \
                    mreg[bn][s * 4 + r] = pmrow[(size_t)(s * 16 + r) * 64 + tn]; \
            __builtin_amdgcn_sched_barrier(0);                                  \
        }                                                                       \
        const char* kl = lds + (CUR) * 16384;                                   \
        f32x4 sacc[2][2];                                                       \
        sacc[0][0] = (f32x4){0.f, 0.f, 0.f, 0.f};                               \
        sacc[0][1] = (f32x4){0.f, 0.f, 0.f, 0.f};                               \
        sacc[1][0] = (f32x4){0.f, 0.f, 0.f, 0.f};                               \
        sacc[1][1] = (f32x4){0.f, 0.f, 0.f, 0.f};                               \
        _Pragma("unroll")                                                       \
        for (int ks = 0; ks < 8; ++ks) {                                        \
            _Pragma("unroll")                                                   \
            for (int nt = 0; nt < 2; ++nt) {                                    \
                const int off = ((nt * 16 + ln15) << 9)                         \
                              + (((ks << 6) + (quad << 4)) ^ swzK);             \
                const bf16x8 bk = *(const bf16x8*)(kl + off);                   \
                sacc[0][nt] = __builtin_amdgcn_mfma_f32_16x16x32_bf16(aq[0][ks], bk, sacc[0][nt], 0, 0, 0); \
                sacc[1][nt] = __builtin_amdgcn_mfma_f32_16x16x32_bf16(aq[1][ks], bk, sacc[1][nt], 0, 0, 0); \
            }                                                                   \
        }                                                                       \
        _Pragma("unroll")                                                       \
        for (int s = 0; s < 2; ++s) {                                           \
            _Pragma("unroll")                                                   \
            for (int nt = 0; nt < 2; ++nt) {                                    \
                _Pragma("unroll")                                               \
                for (int r = 0; r < 4; ++r) {                                   \
                    const float p = ((mreg[CUR][s * 4 + r] >> (nt * 16 + ln15)) & 1u) \
                                  ? exp2f(sacc[s][nt][r]) : 1.0f;               \
                    const int row  = s * 16 + 4 * quad + r;                     \
                    const int boff = (row << 6)                                 \
                                   + ((nt * 32 + ln15 * 2) ^ (((row >> 1) & 3) << 4)); \
                    *(unsigned short*)(pw + boff) = f2bf(p);                    \
                }                                                               \
            }                                                                   \
        }                                                                       \
        const bf16x8 ap0 = *(const bf16x8*)(pw + (ln15 << 6)        + ((quad << 4) ^ swzA)); \
        const bf16x8 ap1 = *(const bf16x8*)(pw + ((16 + ln15) << 6) + ((quad << 4) ^ swzA)); \
        const char* vl = lds + 65536 + (CUR) * 16384;                           \
        lacc[0] = __builtin_amdgcn_mfma_f32_16x16x32_bf16(ap0, ones, lacc[0], 0, 0, 0); \
        lacc[1] = __builtin_amdgcn_mfma_f32_16x16x32_bf16(ap1, ones, lacc[1], 0, 0, 0); \
        _Pragma("unroll")                                                       \
        for (int nt2 = 0; nt2 < 16; ++nt2) {                                    \
            const int voff = ((nt2 * 16 + ln15) << 6) + ((quad << 4) ^ swzA);   \
            const bf16x8 bv = *(const bf16x8*)(vl + voff);                      \
            oacc[0][nt2] = __builtin_amdgcn_mfma_f32_16x16x32_bf16(ap0, bv, oacc[0][nt2], 0, 0, 0); \
            oacc[1][nt2] = __builtin_amdgcn_mfma_f32_16x16x32_bf16(ap1, bv, oacc[1][nt2], 0, 0, 0); \
        }                                                                       \
    }

    // main loop: phases 0..59 (full pattern), then peeled tail 60..63
    for (int t4 = 0; t4 < 15; ++t4) {
        const int t = t4 * 4;
        PHASE(t + 0, 0, 32, 1);
        PHASE(t + 1, 1, 32, 1);
        PHASE(t + 2, 2, 32, 1);
        PHASE(t + 3, 3, 32, 1);
    }
    PHASE(60, 0, 32, 1);   // issues group 63
    PHASE(61, 1, 32, 0);
    PHASE(62, 2, 16, 0);
    PHASE(63, 3,  0, 0);
#undef PHASE

    // ---- epilogue: normalize and store ----
    #pragma unroll
    for (int s = 0; s < 2; ++s) {
        #pragma unroll
        for (int r = 0; r < 4; ++r) {
            const float inv = 1.0f / lacc[s][r];
            float* orow = out + ((size_t)(b * S_ + qw + s * 16 + 4 * quad + r)) * D_ + ln15;
            #pragma unroll
            for (int nt2 = 0; nt2 < 16; ++nt2)
                orow[nt2 * 16] = oacc[s][nt2][r] * inv;
        }
    }
}

// ---------------- fallback (round-1 kernel, used if ws too small) -----------
#define QT 128
#define KTF 64
#define NW 8
#define KSTR 264
#define VSTR 72
#define PSTR 72

__global__ __launch_bounds__(512, 2)
void attn_fused_v1(const float* __restrict__ q, const float* __restrict__ k,
                   const float* __restrict__ v, const int* __restrict__ mask,
                   float* __restrict__ out)
{
    __shared__ unsigned short Kl[KTF * KSTR];
    __shared__ unsigned short Vt[D_ * VSTR];
    __shared__ unsigned short Pl[NW][16 * PSTR];

    const int tid  = threadIdx.x;
    const int wid  = tid >> 6;
    const int lane = tid & 63;
    const int ln15 = lane & 15;
    const int quad = lane >> 4;
    const int bid = blockIdx.x;
    const int bx  = (bid & 7) * 32 + (bid >> 3);
    const int b  = bx >> 4;
    const int qt = bx & 15;
    const int qw = qt * QT + wid * 16;

    const float* qb = q + ((size_t)b * S_ + qw) * D_;
    const float* kb = k + (size_t)b * S_ * D_;
    const float* vb = v + (size_t)b * S_ * D_;
    const int*   mb = mask + ((size_t)b * S_ + qw) * (size_t)S_;

    bf16x8 aq[8];
    {
        const float* qrow = qb + (size_t)ln15 * D_;
        #pragma unroll
        for (int ks = 0; ks < 8; ++ks) {
            const float4 f0 = *(const float4*)(qrow + ks * 32 + quad * 8);
            const float4 f1 = *(const float4*)(qrow + ks * 32 + quad * 8 + 4);
            bf16x8 a;
            a[0] = (short)f2bf(f0.x * 0.0625f); a[1] = (short)f2bf(f0.y * 0.0625f);
            a[2] = (short)f2bf(f0.z * 0.0625f); a[3] = (short)f2bf(f0.w * 0.0625f);
            a[4] = (short)f2bf(f1.x * 0.0625f); a[5] = (short)f2bf(f1.y * 0.0625f);
            a[6] = (short)f2bf(f1.z * 0.0625f); a[7] = (short)f2bf(f1.w * 0.0625f);
            aq[ks] = a;
        }
    }
    bf16x8 ones;
    #pragma unroll
    for (int e = 0; e < 8; ++e) ones[e] = (short)0x3F80;
    f32x4 oacc[16];
    #pragma unroll
    for (int i = 0; i < 16; ++i) oacc[i] = (f32x4){0.f, 0.f, 0.f, 0.f};
    f32x4 lacc = (f32x4){0.f, 0.f, 0.f, 0.f};
    const int kst_c0 = (tid & 63) * 4;

    for (int kt2 = 0; kt2 < S_ / KTF; ++kt2) {
        const int kvbase = kt2 * KTF;
        int mval[4][4];
        #pragma unroll
        for (int nt = 0; nt < 4; ++nt)
            #pragma unroll
            for (int r = 0; r < 4; ++r)
                mval[nt][r] = mb[(size_t)(4 * quad + r) * S_ + kvbase + nt * 16 + ln15];
        __syncthreads();
        {
            const float* ks_ = kb + (size_t)kvbase * D_;
            #pragma unroll
            for (int pass = 0; pass < 8; ++pass) {
                const int r = pass * 8 + wid;
                const float4 f = *(const float4*)(ks_ + (size_t)r * D_ + kst_c0);
                ushort4 hh;
                hh.x = f2bf(f.x); hh.y = f2bf(f.y); hh.z = f2bf(f.z); hh.w = f2bf(f.w);
                *(ushort4*)&Kl[r * KSTR + kst_c0] = hh;
            }
        }
        {
            const float* vs_ = vb + (size_t)kvbase * D_;
            #pragma unroll
            for (int pass = 0; pass < 8; ++pass) {
                const int idx = pass * 8 + wid;
                const int kv  = (idx & 3) * 16 + ln15;
                const int d0  = (idx >> 2) * 16 + 4 * quad;
                const float4 f = *(const float4*)(vs_ + (size_t)kv * D_ + d0);
                Vt[(d0 + 0) * VSTR + kv] = f2bf(f.x);
                Vt[(d0 + 1) * VSTR + kv] = f2bf(f.y);
                Vt[(d0 + 2) * VSTR + kv] = f2bf(f.z);
                Vt[(d0 + 3) * VSTR + kv] = f2bf(f.w);
            }
        }
        __syncthreads();
        f32x4 sacc[4];
        #pragma unroll
        for (int nt = 0; nt < 4; ++nt) sacc[nt] = (f32x4){0.f, 0.f, 0.f, 0.f};
        #pragma unroll
        for (int ks = 0; ks < 8; ++ks) {
            #pragma unroll
            for (int nt = 0; nt < 4; ++nt) {
                const bf16x8 bk =
                    *(const bf16x8*)&Kl[(nt * 16 + ln15) * KSTR + ks * 32 + quad * 8];
                sacc[nt] = __builtin_amdgcn_mfma_f32_16x16x32_bf16(aq[ks], bk, sacc[nt], 0, 0, 0);
            }
        }
        unsigned short* pwv = Pl[wid];
        #pragma unroll
        for (int nt = 0; nt < 4; ++nt) {
            #pragma unroll
            for (int r = 0; r < 4; ++r) {
                const float s = sacc[nt][r];
                const float p = (mval[nt][r] != 0) ? __expf(s) : 1.0f;
                pwv[(4 * quad + r) * PSTR + nt * 16 + ln15] = f2bf(p);
            }
        }
        #pragma unroll
        for (int ks2 = 0; ks2 < 2; ++ks2) {
            const bf16x8 ap = *(const bf16x8*)&pwv[ln15 * PSTR + ks2 * 32 + quad * 8];
            lacc = __builtin_amdgcn_mfma_f32_16x16x32_bf16(ap, ones, lacc, 0, 0, 0);
            #pragma unroll
            for (int nt2 = 0; nt2 < 16; ++nt2) {
                const bf16x8 bv =
                    *(const bf16x8*)&Vt[(nt2 * 16 + ln15) * VSTR + ks2 * 32 + quad * 8];
                oacc[nt2] = __builtin_amdgcn_mfma_f32_16x16x32_bf16(ap, bv, oacc[nt2], 0, 0, 0);
            }
        }
    }
    #pragma unroll
    for (int r = 0; r < 4; ++r) {
        const float inv = 1.0f / lacc[r];
        float* orow = out + ((size_t)b * S_ + qw + 4 * quad + r) * D_ + ln15;
        #pragma unroll
        for (int nt2 = 0; nt2 < 16; ++nt2)
            orow[nt2 * 16] = oacc[nt2][r] * inv;
    }
}

extern "C" void kernel_launch(void* const* d_in, const int* in_sizes, int n_in,
                              void* d_out, int out_size, void* d_ws, size_t ws_size,
                              hipStream_t stream) {
    const float* q    = (const float*)d_in[0];
    const float* k    = (const float*)d_in[1];
    const float* v    = (const float*)d_in[2];
    const int*   mask = (const int*)d_in[3];
    float*       out  = (float*)d_out;

    const size_t one  = (size_t)B_ * NT_ * TILE_BYTES;            // 16.78 MB
    const size_t pmsz = (size_t)B_ * S_ * 64 * 4;                 //  8.39 MB
    if (ws_size >= 2 * one + pmsz) {
        char*     kbf  = (char*)d_ws;
        char*     vtbf = kbf + one;
        unsigned* pmp  = (unsigned*)(vtbf + one);
        prep_all<<<12288, 256, 0, stream>>>(k, v, mask, kbf, vtbf, pmp);
        attn_main<<<256, 256, 0, stream>>>(q, pmp, kbf, vtbf, out);
    } else {
        attn_fused_v1<<<256, 512, 0, stream>>>(q, k, v, mask, out);
    }
}

// Round 16
// 159.413 us; speedup vs baseline: 1.2926x; 1.2821x over previous
//
#include <hip/hip_runtime.h>

// Attention, non-standard masking (masked scores -> 0.0 before softmax).
// B=16, S=2048, D=256, fp32 in/out. No-max streaming softmax (scores ~N(0,1)).
// exp2-based: Q pre-scaled by log2e/16.
//
// FINAL (= v9, session-best 159.4us total): counted-vmcnt quad-buffered
// K/V pipeline (global_load_lds, prefetch distance 3, phase-top
// s_waitcnt vmcnt(48), raw s_barrier), with the raw mask streamed in-loop
// as plain dword loads issued at END of phase, prefetch distance 2.
// prep_all converts K -> bf16 pre-swizzled [32kv][512B] tile images and
// V -> bf16 transposed [256d][64B] images (L3-resident, ~7us).
//
// Session evidence (16 rounds): mask-in-L2 attn = 95us but any pack path
// pays >= the same 268MB HBM crossing (total >= 175us); in-kernel raw
// streaming at 128B/8KB granularity is DRAM-row-activation limited
// (~1.65 TB/s) -> attn ~162us; all fusion/split/pack alternatives measured
// worse (172-225us). This configuration is the measured optimum.

#define B_  16
#define S_  2048
#define D_  256
#define NT_ 64            // 32-kv tiles per batch
#define TILE_BYTES 16384

typedef short bf16x8 __attribute__((ext_vector_type(8)));
typedef float f32x4  __attribute__((ext_vector_type(4)));

__device__ __forceinline__ unsigned short f2bf(float x) {
    union { float f; unsigned u; } c; c.f = x;
    unsigned u = c.u;
    u += 0x7FFFu + ((u >> 16) & 1u);   // round-to-nearest-even
    return (unsigned short)(u >> 16);
}

#define GLDS(g, l) __builtin_amdgcn_global_load_lds( \
    (const __attribute__((address_space(1))) void*)(g), \
    (__attribute__((address_space(3))) void*)(l), 16, 0, 0)

#define WAITVM(N) asm volatile("s_waitcnt vmcnt(" #N ")" ::: "memory")

// ---------------- prepass: K/V -> bf16 pre-swizzled tile images -------------
// bid [0,4096):    K -> [32kv][512B] img, byte(kv,d)=kv*512 + (d*2 ^ ((kv&7)<<4))
// bid [4096,8192): V -> [256d][64B] img, byte(d,kv)=d*64 + (kv*2 ^ (((d>>1)&3)<<4))
__global__ __launch_bounds__(256)
void prep_all(const float* __restrict__ k, const float* __restrict__ v,
              char* __restrict__ kbf, char* __restrict__ vtbf)
{
    const int bid = blockIdx.x;
    if (bid < 4096) {
        const int gid = bid * 256 + threadIdx.x;          // 2^20 threads
        const int d8  = gid & 31;
        const int kv  = (gid >> 5) & 2047;
        const int b   = gid >> 16;
        const float* src = k + (((size_t)(b * S_ + kv)) << 8) + d8 * 8;
        const float4 f0 = *(const float4*)src;
        const float4 f1 = *(const float4*)(src + 4);
        bf16x8 h;
        h[0] = (short)f2bf(f0.x); h[1] = (short)f2bf(f0.y);
        h[2] = (short)f2bf(f0.z); h[3] = (short)f2bf(f0.w);
        h[4] = (short)f2bf(f1.x); h[5] = (short)f2bf(f1.y);
        h[6] = (short)f2bf(f1.z); h[7] = (short)f2bf(f1.w);
        const int tile = kv >> 5, kvl = kv & 31;
        char* dst = kbf + (((size_t)(b * NT_ + tile)) << 14)
                        + (kvl << 9) + ((d8 * 16) ^ ((kvl & 7) << 4));
        *(bf16x8*)dst = h;
    } else {
        const int gid  = (bid - 4096) * 256 + threadIdx.x;
        const int d    = gid & 255;
        const int g    = (gid >> 8) & 3;                  // kv group of 8
        const int tile = (gid >> 10) & 63;
        const int b    = gid >> 16;
        const int kv0  = tile * 32 + g * 8;
        const float* src = v + (((size_t)(b * S_ + kv0)) << 8) + d;
        bf16x8 h;
        #pragma unroll
        for (int j = 0; j < 8; ++j) h[j] = (short)f2bf(src[(size_t)j << 8]);
        char* dst = vtbf + (((size_t)(b * NT_ + tile)) << 14)
                         + (d << 6) + ((g * 16) ^ (((d >> 1) & 3) << 4));
        *(bf16x8*)dst = h;
    }
}

// --------------------------------- main -------------------------------------
// 256 thr / 4 waves; wave wid owns q-rows qt*128 + wid*32 .. +32; all 64 tiles.
__global__ __launch_bounds__(256, 1)
void attn_main(const float* __restrict__ q, const int* __restrict__ mask,
               const char* __restrict__ kbf, const char* __restrict__ vtbf,
               float* __restrict__ out)
{
    // [0,65536) K quad-buf; [65536,131072) Vt quad-buf; [131072,139264) P
    __shared__ alignas(128) char lds[139264];

    const int tid  = threadIdx.x;
    const int wid  = tid >> 6;
    const int lane = tid & 63;
    const int ln15 = lane & 15;
    const int quad = lane >> 4;
    const int swzK = (ln15 & 7) << 4;          // K row XOR key (bits 4-6)
    const int swzA = ((ln15 >> 1) & 3) << 4;   // Vt/P row XOR key (bits 4-5)

    const int bid = blockIdx.x;
    const int bx  = (bid & 7) * 32 + (bid >> 3);   // XCD-chunked swizzle
    const int b   = bx >> 4;
    const int qt  = bx & 15;
    const int qw  = qt * 128 + wid * 32;           // wave owns 32 q-rows

    // Q A-fragments (2 sets of 16 rows), pre-scaled by log2(e)/sqrt(256)
    const float QS = 0.09016844f;
    bf16x8 aq[2][8];
    #pragma unroll
    for (int s = 0; s < 2; ++s) {
        const float* qrow = q + ((size_t)(b * S_ + qw + s * 16 + ln15)) * D_;
        #pragma unroll
        for (int ks = 0; ks < 8; ++ks) {
            const float4 f0 = *(const float4*)(qrow + ks * 32 + quad * 8);
            const float4 f1 = *(const float4*)(qrow + ks * 32 + quad * 8 + 4);
            bf16x8 a;
            a[0] = (short)f2bf(f0.x * QS); a[1] = (short)f2bf(f0.y * QS);
            a[2] = (short)f2bf(f0.z * QS); a[3] = (short)f2bf(f0.w * QS);
            a[4] = (short)f2bf(f1.x * QS); a[5] = (short)f2bf(f1.y * QS);
            a[6] = (short)f2bf(f1.z * QS); a[7] = (short)f2bf(f1.w * QS);
            aq[s][ks] = a;
        }
    }
    __builtin_amdgcn_sched_barrier(0);   // Q loads retired before staging

    bf16x8 ones;
    #pragma unroll
    for (int e = 0; e < 8; ++e) ones[e] = (short)0x3F80;

    f32x4 oacc[2][16];
    #pragma unroll
    for (int s = 0; s < 2; ++s)
        #pragma unroll
        for (int i = 0; i < 16; ++i) oacc[s][i] = (f32x4){0.f, 0.f, 0.f, 0.f};
    f32x4 lacc[2];
    lacc[0] = (f32x4){0.f, 0.f, 0.f, 0.f};
    lacc[1] = (f32x4){0.f, 0.f, 0.f, 0.f};

    const char* ktile = kbf  + (((size_t)b * NT_) << 14);
    const char* vtile = vtbf + (((size_t)b * NT_) << 14);
    char* pw = lds + 131072 + wid * 2048;
    const int cc = wid * 4;   // this wave's 4 staging chunks (of 16) per tile

    // raw mask rows for this lane (rows qw+4*quad+{0..3}+16s; 4B/elem)
    const int* mbase = mask + ((size_t)(b * S_ + qw + 4 * quad)) * S_;
    int mreg[4][16];

    // ---- prologue: GLDS tiles 0,1,2 (24 ops), then mask tiles 0,1 (32 ops) ----
    #pragma unroll
    for (int t = 0; t < 3; ++t) {
        #pragma unroll
        for (int c = 0; c < 4; ++c) {
            GLDS(ktile + t * 16384 + (cc + c) * 1024 + lane * 16,
                 lds +         t * 16384 + (cc + c) * 1024);
            GLDS(vtile + t * 16384 + (cc + c) * 1024 + lane * 16,
                 lds + 65536 + t * 16384 + (cc + c) * 1024);
        }
    }
    __builtin_amdgcn_sched_barrier(0);
    #pragma unroll
    for (int t = 0; t < 2; ++t)
        #pragma unroll
        for (int s = 0; s < 2; ++s)
            #pragma unroll
            for (int nt = 0; nt < 2; ++nt)
                #pragma unroll
                for (int r = 0; r < 4; ++r)
                    mreg[t][s * 8 + nt * 4 + r] =
                        mbase[(size_t)(s * 16 + r) * S_ + t * 32 + nt * 16 + ln15];
    __builtin_amdgcn_sched_barrier(0);

#define PHASE(T, CUR, CNT, GISS, MISS)                                          \
    {                                                                           \
        WAITVM(CNT);                                                            \
        __builtin_amdgcn_sched_barrier(0);                                      \
        __builtin_amdgcn_s_barrier();                                           \
        __builtin_amdgcn_sched_barrier(0);                                      \
        if (GISS) {                                                             \
            const int tn  = (T) + 3;                                            \
            const int bn  = ((CUR) + 3) & 3;                                    \
            const char* kg_ = ktile + ((size_t)tn << 14);                       \
            const char* vg_ = vtile + ((size_t)tn << 14);                       \
            _Pragma("unroll")                                                   \
            for (int c = 0; c < 4; ++c) {                                       \
                GLDS(kg_ + (cc + c) * 1024 + lane * 16,                         \
                     lds + bn * 16384 +         (cc + c) * 1024);               \
                GLDS(vg_ + (cc + c) * 1024 + lane * 16,                         \
                     lds + 65536 + bn * 16384 + (cc + c) * 1024);               \
            }                                                                   \
            __builtin_amdgcn_sched_barrier(0);                                  \
        }                                                                       \
        const char* kl = lds + (CUR) * 16384;                                   \
        f32x4 sacc[2][2];                                                       \
        sacc[0][0] = (f32x4){0.f, 0.f, 0.f, 0.f};                               \
        sacc[0][1] = (f32x4){0.f, 0.f, 0.f, 0.f};                               \
        sacc[1][0] = (f32x4){0.f, 0.f, 0.f, 0.f};                               \
        sacc[1][1] = (f32x4){0.f, 0.f, 0.f, 0.f};                               \
        _Pragma("unroll")                                                       \
        for (int ks = 0; ks < 8; ++ks) {                                        \
            _Pragma("unroll")                                                   \
            for (int nt = 0; nt < 2; ++nt) {                                    \
                const int off = ((nt * 16 + ln15) << 9)                         \
                              + (((ks << 6) + (quad << 4)) ^ swzK);             \
                const bf16x8 bk = *(const bf16x8*)(kl + off);                   \
                sacc[0][nt] = __builtin_amdgcn_mfma_f32_16x16x32_bf16(aq[0][ks], bk, sacc[0][nt], 0, 0, 0); \
                sacc[1][nt] = __builtin_amdgcn_mfma_f32_16x16x32_bf16(aq[1][ks], bk, sacc[1][nt], 0, 0, 0); \
            }                                                                   \
        }                                                                       \
        _Pragma("unroll")                                                       \
        for (int s = 0; s < 2; ++s) {                                           \
            _Pragma("unroll")                                                   \
            for (int nt = 0; nt < 2; ++nt) {                                    \
                _Pragma("unroll")                                               \
                for (int r = 0; r < 4; ++r) {                                   \
                    const float p = (mreg[CUR][s * 8 + nt * 4 + r] != 0)        \
                                  ? exp2f(sacc[s][nt][r]) : 1.0f;               \
                    const int row  = s * 16 + 4 * quad + r;                     \
                    const int boff = (row << 6)                                 \
                                   + ((nt * 32 + ln15 * 2) ^ (((row >> 1) & 3) << 4)); \
                    *(unsigned short*)(pw + boff) = f2bf(p);                    \
                }                                                               \
            }                                                                   \
        }                                                                       \
        const bf16x8 ap0 = *(const bf16x8*)(pw + (ln15 << 6)        + ((quad << 4) ^ swzA)); \
        const bf16x8 ap1 = *(const bf16x8*)(pw + ((16 + ln15) << 6) + ((quad << 4) ^ swzA)); \
        const char* vl = lds + 65536 + (CUR) * 16384;                           \
        lacc[0] = __builtin_amdgcn_mfma_f32_16x16x32_bf16(ap0, ones, lacc[0], 0, 0, 0); \
        lacc[1] = __builtin_amdgcn_mfma_f32_16x16x32_bf16(ap1, ones, lacc[1], 0, 0, 0); \
        _Pragma("unroll")                                                       \
        for (int nt2 = 0; nt2 < 16; ++nt2) {                                    \
            const int voff = ((nt2 * 16 + ln15) << 6) + ((quad << 4) ^ swzA);   \
            const bf16x8 bv = *(const bf16x8*)(vl + voff);                      \
            oacc[0][nt2] = __builtin_amdgcn_mfma_f32_16x16x32_bf16(ap0, bv, oacc[0][nt2], 0, 0, 0); \
            oacc[1][nt2] = __builtin_amdgcn_mfma_f32_16x16x32_bf16(ap1, bv, oacc[1][nt2], 0, 0, 0); \
        }                                                                       \
        __builtin_amdgcn_sched_barrier(0);                                      \
        if (MISS) {                                                             \
            const int tm = (T) + 2;                                             \
            const int bm = ((CUR) + 2) & 3;                                     \
            _Pragma("unroll")                                                   \
            for (int s = 0; s < 2; ++s)                                         \
                _Pragma("unroll")                                               \
                for (int nt = 0; nt < 2; ++nt)                                  \
                    _Pragma("unroll")                                           \
                    for (int r = 0; r < 4; ++r)                                 \
                        mreg[bm][s * 8 + nt * 4 + r] =                          \
                            mbase[(size_t)(s * 16 + r) * S_ + tm * 32 + nt * 16 + ln15]; \
            __builtin_amdgcn_sched_barrier(0);                                  \
        }                                                                       \
    }

    // main loop: phases 0..59 (full pattern), then peeled tail 60..63
    for (int t4 = 0; t4 < 15; ++t4) {
        const int t = t4 * 4;
        PHASE(t + 0, 0, 48, 1, 1);
        PHASE(t + 1, 1, 48, 1, 1);
        PHASE(t + 2, 2, 48, 1, 1);
        PHASE(t + 3, 3, 48, 1, 1);
    }
    PHASE(60, 0, 48, 1, 1);   // issues GLDS 63, mask 62
    PHASE(61, 1, 48, 0, 1);   // issues mask 63
    PHASE(62, 2, 40, 0, 0);
    PHASE(63, 3, 16, 0, 0);
#undef PHASE

    // ---- epilogue: normalize and store ----
    #pragma unroll
    for (int s = 0; s < 2; ++s) {
        #pragma unroll
        for (int r = 0; r < 4; ++r) {
            const float inv = 1.0f / lacc[s][r];
            float* orow = out + ((size_t)(b * S_ + qw + s * 16 + 4 * quad + r)) * D_ + ln15;
            #pragma unroll
            for (int nt2 = 0; nt2 < 16; ++nt2)
                orow[nt2 * 16] = oacc[s][nt2][r] * inv;
        }
    }
}

// ---------------- fallback (round-1 kernel, used if ws too small) -----------
#define QT 128
#define KTF 64
#define NW 8
#define KSTR 264
#define VSTR 72
#define PSTR 72

__global__ __launch_bounds__(512, 2)
void attn_fused_v1(const float* __restrict__ q, const float* __restrict__ k,
                   const float* __restrict__ v, const int* __restrict__ mask,
                   float* __restrict__ out)
{
    __shared__ unsigned short Kl[KTF * KSTR];
    __shared__ unsigned short Vt[D_ * VSTR];
    __shared__ unsigned short Pl[NW][16 * PSTR];

    const int tid  = threadIdx.x;
    const int wid  = tid >> 6;
    const int lane = tid & 63;
    const int ln15 = lane & 15;
    const int quad = lane >> 4;
    const int bid = blockIdx.x;
    const int bx  = (bid & 7) * 32 + (bid >> 3);
    const int b  = bx >> 4;
    const int qt = bx & 15;
    const int qw = qt * QT + wid * 16;

    const float* qb = q + ((size_t)b * S_ + qw) * D_;
    const float* kb = k + (size_t)b * S_ * D_;
    const float* vb = v + (size_t)b * S_ * D_;
    const int*   mb = mask + ((size_t)b * S_ + qw) * (size_t)S_;

    bf16x8 aq[8];
    {
        const float* qrow = qb + (size_t)ln15 * D_;
        #pragma unroll
        for (int ks = 0; ks < 8; ++ks) {
            const float4 f0 = *(const float4*)(qrow + ks * 32 + quad * 8);
            const float4 f1 = *(const float4*)(qrow + ks * 32 + quad * 8 + 4);
            bf16x8 a;
            a[0] = (short)f2bf(f0.x * 0.0625f); a[1] = (short)f2bf(f0.y * 0.0625f);
            a[2] = (short)f2bf(f0.z * 0.0625f); a[3] = (short)f2bf(f0.w * 0.0625f);
            a[4] = (short)f2bf(f1.x * 0.0625f); a[5] = (short)f2bf(f1.y * 0.0625f);
            a[6] = (short)f2bf(f1.z * 0.0625f); a[7] = (short)f2bf(f1.w * 0.0625f);
            aq[ks] = a;
        }
    }
    bf16x8 ones;
    #pragma unroll
    for (int e = 0; e < 8; ++e) ones[e] = (short)0x3F80;
    f32x4 oacc[16];
    #pragma unroll
    for (int i = 0; i < 16; ++i) oacc[i] = (f32x4){0.f, 0.f, 0.f, 0.f};
    f32x4 lacc = (f32x4){0.f, 0.f, 0.f, 0.f};
    const int kst_c0 = (tid & 63) * 4;

    for (int kt2 = 0; kt2 < S_ / KTF; ++kt2) {
        const int kvbase = kt2 * KTF;
        int mval[4][4];
        #pragma unroll
        for (int nt = 0; nt < 4; ++nt)
            #pragma unroll
            for (int r = 0; r < 4; ++r)
                mval[nt][r] = mb[(size_t)(4 * quad + r) * S_ + kvbase + nt * 16 + ln15];
        __syncthreads();
        {
            const float* ks_ = kb + (size_t)kvbase * D_;
            #pragma unroll
            for (int pass = 0; pass < 8; ++pass) {
                const int r = pass * 8 + wid;
                const float4 f = *(const float4*)(ks_ + (size_t)r * D_ + kst_c0);
                ushort4 hh;
                hh.x = f2bf(f.x); hh.y = f2bf(f.y); hh.z = f2bf(f.z); hh.w = f2bf(f.w);
                *(ushort4*)&Kl[r * KSTR + kst_c0] = hh;
            }
        }
        {
            const float* vs_ = vb + (size_t)kvbase * D_;
            #pragma unroll
            for (int pass = 0; pass < 8; ++pass) {
                const int idx = pass * 8 + wid;
                const int kv  = (idx & 3) * 16 + ln15;
                const int d0  = (idx >> 2) * 16 + 4 * quad;
                const float4 f = *(const float4*)(vs_ + (size_t)kv * D_ + d0);
                Vt[(d0 + 0) * VSTR + kv] = f2bf(f.x);
                Vt[(d0 + 1) * VSTR + kv] = f2bf(f.y);
                Vt[(d0 + 2) * VSTR + kv] = f2bf(f.z);
                Vt[(d0 + 3) * VSTR + kv] = f2bf(f.w);
            }
        }
        __syncthreads();
        f32x4 sacc[4];
        #pragma unroll
        for (int nt = 0; nt < 4; ++nt) sacc[nt] = (f32x4){0.f, 0.f, 0.f, 0.f};
        #pragma unroll
        for (int ks = 0; ks < 8; ++ks) {
            #pragma unroll
            for (int nt = 0; nt < 4; ++nt) {
                const bf16x8 bk =
                    *(const bf16x8*)&Kl[(nt * 16 + ln15) * KSTR + ks * 32 + quad * 8];
                sacc[nt] = __builtin_amdgcn_mfma_f32_16x16x32_bf16(aq[ks], bk, sacc[nt], 0, 0, 0);
            }
        }
        unsigned short* pwv = Pl[wid];
        #pragma unroll
        for (int nt = 0; nt < 4; ++nt) {
            #pragma unroll
            for (int r = 0; r < 4; ++r) {
                const float s = sacc[nt][r];
                const float p = (mval[nt][r] != 0) ? __expf(s) : 1.0f;
                pwv[(4 * quad + r) * PSTR + nt * 16 + ln15] = f2bf(p);
            }
        }
        #pragma unroll
        for (int ks2 = 0; ks2 < 2; ++ks2) {
            const bf16x8 ap = *(const bf16x8*)&pwv[ln15 * PSTR + ks2 * 32 + quad * 8];
            lacc = __builtin_amdgcn_mfma_f32_16x16x32_bf16(ap, ones, lacc, 0, 0, 0);
            #pragma unroll
            for (int nt2 = 0; nt2 < 16; ++nt2) {
                const bf16x8 bv =
                    *(const bf16x8*)&Vt[(nt2 * 16 + ln15) * VSTR + ks2 * 32 + quad * 8];
                oacc[nt2] = __builtin_amdgcn_mfma_f32_16x16x32_bf16(ap, bv, oacc[nt2], 0, 0, 0);
            }
        }
    }
    #pragma unroll
    for (int r = 0; r < 4; ++r) {
        const float inv = 1.0f / lacc[r];
        float* orow = out + ((size_t)b * S_ + qw + 4 * quad + r) * D_ + ln15;
        #pragma unroll
        for (int nt2 = 0; nt2 < 16; ++nt2)
            orow[nt2 * 16] = oacc[nt2][r] * inv;
    }
}

extern "C" void kernel_launch(void* const* d_in, const int* in_sizes, int n_in,
                              void* d_out, int out_size, void* d_ws, size_t ws_size,
                              hipStream_t stream) {
    const float* q    = (const float*)d_in[0];
    const float* k    = (const float*)d_in[1];
    const float* v    = (const float*)d_in[2];
    const int*   mask = (const int*)d_in[3];
    float*       out  = (float*)d_out;

    const size_t one = (size_t)B_ * NT_ * TILE_BYTES;   // 16.78 MB
    if (ws_size >= 2 * one) {
        char* kbf  = (char*)d_ws;
        char* vtbf = kbf + one;
        prep_all<<<8192, 256, 0, stream>>>(k, v, kbf, vtbf);
        attn_main<<<256, 256, 0, stream>>>(q, mask, kbf, vtbf, out);
    } else {
        attn_fused_v1<<<256, 512, 0, stream>>>(q, k, v, mask, out);
    }
}